// Round 5
// baseline (368.318 us; speedup 1.0000x reference)
//
#include <hip/hip_runtime.h>

// GCNPredictor: 3-layer GCN (sum-aggregation) + sum-pool + MLP head, fp32.
// Round 5: group-coalesced gather. 16 groups x 32 lanes per 512-thread block;
// a group reads one full 512B src row per edge (lane-uniform src -> ~2 row
// addresses per wave-instruction instead of 64 scattered), 4 edges in flight
// via independent partial accumulators.

constexpr int NUM_GRAPHS = 2048;

// ---------------- h0 = x @ W_emb  ([N,35] @ [35,8]) ----------------
__global__ __launch_bounds__(256) void k_embed(const float* __restrict__ x,
                                               const float* __restrict__ Wemb,
                                               float* __restrict__ h0, int N) {
  __shared__ float sx[32 * 35];
  __shared__ float sw[35 * 8];
  int n0 = blockIdx.x * 32;
  int cnt = min(32, N - n0);
  int nf = cnt * 35;
  for (int i = threadIdx.x; i < nf; i += 256) sx[i] = x[(size_t)n0 * 35 + i];
  for (int i = threadIdx.x; i < 35 * 8; i += 256) sw[i] = Wemb[i];
  __syncthreads();
  int nl = threadIdx.x >> 3;
  int c = threadIdx.x & 7;
  if (nl < cnt) {
    float acc = 0.f;
#pragma unroll
    for (int k = 0; k < 35; ++k) acc = fmaf(sx[nl * 35 + k], sw[k * 8 + c], acc);
    h0[(size_t)(n0 + nl) * 8 + c] = acc;
  }
}

// ---------------- CSR build: counts -> exclusive scan -> fill ----------------
__global__ __launch_bounds__(256) void k_hist(const int* __restrict__ dst,
                                              int* counts, int E) {
  int e = blockIdx.x * 256 + threadIdx.x;
  if (e < E) atomicAdd(&counts[dst[e]], 1);
}

__global__ __launch_bounds__(256) void k_scan1(const int* __restrict__ counts,
                                               int* __restrict__ offs,
                                               int* __restrict__ partials, int N) {
  __shared__ int s[256];
  int i = blockIdx.x * 256 + threadIdx.x;
  int v = (i < N) ? counts[i] : 0;
  s[threadIdx.x] = v;
  __syncthreads();
#pragma unroll
  for (int d = 1; d < 256; d <<= 1) {
    int t = (threadIdx.x >= d) ? s[threadIdx.x - d] : 0;
    __syncthreads();
    s[threadIdx.x] += t;
    __syncthreads();
  }
  if (i < N) offs[i] = s[threadIdx.x] - v;  // exclusive
  if (threadIdx.x == 255) partials[blockIdx.x] = s[255];
}

__global__ __launch_bounds__(512) void k_scan2(int* partials, int nb) {
  __shared__ int s[512];
  int t = threadIdx.x;
  int orig = (t < nb) ? partials[t] : 0;
  s[t] = orig;
  __syncthreads();
#pragma unroll
  for (int d = 1; d < 512; d <<= 1) {
    int v = (t >= d) ? s[t - d] : 0;
    __syncthreads();
    s[t] += v;
    __syncthreads();
  }
  if (t < nb) partials[t] = s[t] - orig;  // exclusive block offsets
}

__global__ __launch_bounds__(256) void k_scan3(int* __restrict__ offs,
                                               const int* __restrict__ partials,
                                               int* __restrict__ cursor, int N) {
  int i = blockIdx.x * 256 + threadIdx.x;
  if (i < N) {
    int v = offs[i] + partials[blockIdx.x];
    offs[i] = v;
    cursor[i] = v;
  }
}

__global__ __launch_bounds__(256) void k_fill(const int* __restrict__ src,
                                              const int* __restrict__ dst,
                                              int* cursor, int* __restrict__ csr,
                                              int E) {
  int e = blockIdx.x * 256 + threadIdx.x;
  if (e < E) {
    int slot = atomicAdd(&cursor[dst[e]], 1);
    csr[slot] = src[e];
  }
}

// -------- layer 0 fused: agg8 = gather(h0); out = relu(agg8 @ W_g0) --------
__global__ __launch_bounds__(256) void k_layer0(const float* __restrict__ h0,
                                                const int* __restrict__ csr,
                                                const int* __restrict__ offs,
                                                const int* __restrict__ cnts,
                                                const float* __restrict__ W,
                                                float* __restrict__ out, int N) {
  __shared__ float sagg[32 * 9];  // stride 9: conflict-free
  __shared__ float sw[8 * 128];
  for (int i = threadIdx.x; i < 1024; i += 256) sw[i] = W[i];
  int n0 = blockIdx.x * 32;
  {
    int i = threadIdx.x >> 3;
    int c = threadIdx.x & 7;
    int n = n0 + i;
    float acc = 0.f;
    if (n < N) {
      int s = offs[n], cc = cnts[n];
      for (int e = 0; e < cc; ++e) acc += h0[(size_t)csr[s + e] * 8 + c];
    }
    sagg[i * 9 + c] = acc;
  }
  __syncthreads();
  int i2 = threadIdx.x >> 3;
  int j0 = (threadIdx.x & 7) * 16;
  int n2 = n0 + i2;
  if (n2 >= N) return;
  float a[8];
#pragma unroll
  for (int k = 0; k < 8; ++k) a[k] = sagg[i2 * 9 + k];
  float o[16];
#pragma unroll
  for (int j = 0; j < 16; ++j) o[j] = 0.f;
#pragma unroll
  for (int k = 0; k < 8; ++k)
#pragma unroll
    for (int j = 0; j < 16; ++j) o[j] = fmaf(a[k], sw[k * 128 + j0 + j], o[j]);
  size_t base = (size_t)n2 * 128 + j0;
#pragma unroll
  for (int t = 0; t < 4; ++t) {
    float4 v;
    v.x = fmaxf(o[t * 4 + 0], 0.f);
    v.y = fmaxf(o[t * 4 + 1], 0.f);
    v.z = fmaxf(o[t * 4 + 2], 0.f);
    v.w = fmaxf(o[t * 4 + 3], 0.f);
    *reinterpret_cast<float4*>(&out[base + t * 4]) = v;
  }
}

// -------- fused GCN layer (d=128): agg = gather(H); v = relu(agg@W) + H --------
// Gather: group g (of 16, 32 lanes each) owns nodes n0+g, +16, +32, +48.
// Per edge the group reads the full 512B src row coalesced (lane-uniform src);
// 4 edges in flight via independent partial accumulators.
// mode 0: out[n] = v. mode 1: G[gid[n]] += v (pool fused).
__global__ __launch_bounds__(512) void k_gcn_fused(
    const float* __restrict__ H, const int* __restrict__ csr,
    const int* __restrict__ offs, const int* __restrict__ cnts,
    const float* __restrict__ W, float* __restrict__ out,
    float* G, const int* __restrict__ gid, int N, int mode) {
  __shared__ float sa[64 * 132];
  int n0 = blockIdx.x * 64;

  // gather phase
  {
    int grp = threadIdx.x >> 5;   // 0..15
    int lane = threadIdx.x & 31;  // 0..31
    int c4 = lane * 4;
    for (int i = grp; i < 64; i += 16) {
      int n = n0 + i;
      float4 a0 = {0.f, 0.f, 0.f, 0.f}, a1 = a0, a2 = a0, a3 = a0;
      if (n < N) {
        int s = offs[n], cnt = cnts[n];
        int e = 0;
        for (; e + 4 <= cnt; e += 4) {
          int s0 = csr[s + e], s1 = csr[s + e + 1];
          int s2 = csr[s + e + 2], s3 = csr[s + e + 3];
          float4 v0 = *reinterpret_cast<const float4*>(&H[(size_t)s0 * 128 + c4]);
          float4 v1 = *reinterpret_cast<const float4*>(&H[(size_t)s1 * 128 + c4]);
          float4 v2 = *reinterpret_cast<const float4*>(&H[(size_t)s2 * 128 + c4]);
          float4 v3 = *reinterpret_cast<const float4*>(&H[(size_t)s3 * 128 + c4]);
          a0.x += v0.x; a0.y += v0.y; a0.z += v0.z; a0.w += v0.w;
          a1.x += v1.x; a1.y += v1.y; a1.z += v1.z; a1.w += v1.w;
          a2.x += v2.x; a2.y += v2.y; a2.z += v2.z; a2.w += v2.w;
          a3.x += v3.x; a3.y += v3.y; a3.z += v3.z; a3.w += v3.w;
        }
        for (; e < cnt; ++e) {
          int s0 = csr[s + e];
          float4 v = *reinterpret_cast<const float4*>(&H[(size_t)s0 * 128 + c4]);
          a0.x += v.x; a0.y += v.y; a0.z += v.z; a0.w += v.w;
        }
      }
      float4 t;
      t.x = (a0.x + a1.x) + (a2.x + a3.x);
      t.y = (a0.y + a1.y) + (a2.y + a3.y);
      t.z = (a0.z + a1.z) + (a2.z + a3.z);
      t.w = (a0.w + a1.w) + (a2.w + a3.w);
      *reinterpret_cast<float4*>(&sa[i * 132 + c4]) = t;
    }
  }
  __syncthreads();

  // GEMM 64x128 @ 128x128 with 512 threads: 32 row-threads x 16 col-threads
  int nl = threadIdx.x >> 4;        // 0..31
  int j0 = (threadIdx.x & 15) * 8;  // 0..120
  float acc[2][8];
#pragma unroll
  for (int r = 0; r < 2; ++r)
#pragma unroll
    for (int j = 0; j < 8; ++j) acc[r][j] = 0.f;
  const float* Wj = W + j0;
#pragma unroll 2
  for (int k = 0; k < 128; ++k) {
    float4 w0 = *reinterpret_cast<const float4*>(Wj + (size_t)k * 128);
    float4 w1 = *reinterpret_cast<const float4*>(Wj + (size_t)k * 128 + 4);
    float wv[8] = {w0.x, w0.y, w0.z, w0.w, w1.x, w1.y, w1.z, w1.w};
#pragma unroll
    for (int r = 0; r < 2; ++r) {
      float a = sa[(nl + 32 * r) * 132 + k];
#pragma unroll
      for (int j = 0; j < 8; ++j) acc[r][j] = fmaf(a, wv[j], acc[r][j]);
    }
  }

  if (mode == 0) {
#pragma unroll
    for (int r = 0; r < 2; ++r) {
      int row = nl + 32 * r;
      int n = n0 + row;
      if (n < N) {
        size_t base = (size_t)n * 128 + j0;
        float4 r0 = *reinterpret_cast<const float4*>(&H[base]);
        float4 r1 = *reinterpret_cast<const float4*>(&H[base + 4]);
        float4 o0, o1;
        o0.x = fmaxf(acc[r][0], 0.f) + r0.x;
        o0.y = fmaxf(acc[r][1], 0.f) + r0.y;
        o0.z = fmaxf(acc[r][2], 0.f) + r0.z;
        o0.w = fmaxf(acc[r][3], 0.f) + r0.w;
        o1.x = fmaxf(acc[r][4], 0.f) + r1.x;
        o1.y = fmaxf(acc[r][5], 0.f) + r1.y;
        o1.z = fmaxf(acc[r][6], 0.f) + r1.z;
        o1.w = fmaxf(acc[r][7], 0.f) + r1.w;
        *reinterpret_cast<float4*>(&out[base]) = o0;
        *reinterpret_cast<float4*>(&out[base + 4]) = o1;
      }
    }
  } else {
    __syncthreads();  // all GEMM reads of sa done
#pragma unroll
    for (int r = 0; r < 2; ++r) {
      int row = nl + 32 * r;
      int n = n0 + row;
      if (n < N) {
        size_t base = (size_t)n * 128 + j0;
        float4 r0 = *reinterpret_cast<const float4*>(&H[base]);
        float4 r1 = *reinterpret_cast<const float4*>(&H[base + 4]);
        float* srow = &sa[row * 132 + j0];
        srow[0] = fmaxf(acc[r][0], 0.f) + r0.x;
        srow[1] = fmaxf(acc[r][1], 0.f) + r0.y;
        srow[2] = fmaxf(acc[r][2], 0.f) + r0.z;
        srow[3] = fmaxf(acc[r][3], 0.f) + r0.w;
        srow[4] = fmaxf(acc[r][4], 0.f) + r1.x;
        srow[5] = fmaxf(acc[r][5], 0.f) + r1.y;
        srow[6] = fmaxf(acc[r][6], 0.f) + r1.z;
        srow[7] = fmaxf(acc[r][7], 0.f) + r1.w;
      }
    }
    __syncthreads();
    int grp = threadIdx.x >> 7;  // 0..3 -> rows [16*grp, 16*grp+16)
    int j = threadIdx.x & 127;
    int r0 = grp * 16;
    int nfirst = n0 + r0;
    if (nfirst < N) {
      float pacc = 0.f;
      int cur = gid[nfirst];
      for (int r = r0; r < r0 + 16; ++r) {
        int n = n0 + r;
        if (n >= N) break;
        int g2 = gid[n];
        if (g2 != cur) {
          atomicAdd(&G[(size_t)cur * 128 + j], pacc);
          pacc = 0.f;
          cur = g2;
        }
        pacc += sa[r * 132 + j];
      }
      atomicAdd(&G[(size_t)cur * 128 + j], pacc);
    }
  }
}

// ---------------- pred = relu(g @ W_p1) @ W_p2 + b ----------------
__global__ __launch_bounds__(64) void k_head(const float* __restrict__ g,
                                             const float* __restrict__ W1,
                                             const float* __restrict__ W2,
                                             const float* __restrict__ b,
                                             float* __restrict__ out) {
  int gi = blockIdx.x;
  int j = threadIdx.x;
  __shared__ float sg[128];
  sg[j] = g[(size_t)gi * 128 + j];
  sg[j + 64] = g[(size_t)gi * 128 + 64 + j];
  __syncthreads();
  float acc = 0.f;
#pragma unroll
  for (int k = 0; k < 128; ++k) acc = fmaf(sg[k], W1[k * 64 + j], acc);
  acc = fmaxf(acc, 0.f) * W2[j];
#pragma unroll
  for (int off = 32; off > 0; off >>= 1) acc += __shfl_down(acc, off);
  if (j == 0) out[gi] = acc + b[0];
}

extern "C" void kernel_launch(void* const* d_in, const int* in_sizes, int n_in,
                              void* d_out, int out_size, void* d_ws, size_t ws_size,
                              hipStream_t stream) {
  const float* x    = (const float*)d_in[0];
  const float* Wemb = (const float*)d_in[1];
  const float* Wg0  = (const float*)d_in[2];
  const float* Wg1  = (const float*)d_in[3];
  const float* Wg2  = (const float*)d_in[4];
  const float* Wp1  = (const float*)d_in[5];
  const float* Wp2  = (const float*)d_in[6];
  const float* bp2  = (const float*)d_in[7];
  const int* esrc   = (const int*)d_in[8];
  const int* edst   = (const int*)d_in[9];
  const int* gids   = (const int*)d_in[10];
  int N = in_sizes[0] / 35;
  int E = in_sizes[8];
  float* out = (float*)d_out;

  // workspace layout
  float* h0 = (float*)d_ws;             // N*8
  float* P  = h0 + (size_t)N * 8;       // N*128
  float* Q  = P + (size_t)N * 128;      // N*128
  float* G  = Q + (size_t)N * 128;      // 2048*128
  int* counts   = (int*)(G + (size_t)NUM_GRAPHS * 128);  // N
  int* offs     = counts + N;                            // N
  int* cursor   = offs + N;                              // N
  int* partials = cursor + N;                            // 512
  int* csr      = partials + 512;                        // E

  int nbE = (E + 255) / 256;
  int nbN = (N + 255) / 256;

  // embed (independent)
  k_embed<<<(N + 31) / 32, 256, 0, stream>>>(x, Wemb, h0, N);

  // CSR build
  hipMemsetAsync(counts, 0, (size_t)N * sizeof(int), stream);
  k_hist<<<nbE, 256, 0, stream>>>(edst, counts, E);
  k_scan1<<<nbN, 256, 0, stream>>>(counts, offs, partials, N);
  k_scan2<<<1, 512, 0, stream>>>(partials, nbN);
  k_scan3<<<nbN, 256, 0, stream>>>(offs, partials, cursor, N);
  k_fill<<<nbE, 256, 0, stream>>>(esrc, edst, cursor, csr, E);

  // zero pooled output (layer-2 epilogue atomics accumulate into it)
  hipMemsetAsync(G, 0, (size_t)NUM_GRAPHS * 128 * sizeof(float), stream);

  // layer 0: P = relu(gather(h0) @ W_g0)
  k_layer0<<<(N + 31) / 32, 256, 0, stream>>>(h0, csr, offs, counts, Wg0, P, N);

  // layer 1: Q = relu(gather(P) @ W_g1) + P
  k_gcn_fused<<<(N + 63) / 64, 512, 0, stream>>>(P, csr, offs, counts, Wg1, Q,
                                                 nullptr, nullptr, N, 0);

  // layer 2 + pool: G[gid] += relu(gather(Q) @ W_g2) + Q
  k_gcn_fused<<<(N + 63) / 64, 512, 0, stream>>>(Q, csr, offs, counts, Wg2, nullptr,
                                                 G, gids, N, 1);

  // head
  k_head<<<NUM_GRAPHS, 64, 0, stream>>>(G, Wp1, Wp2, bp2, out);
}

// Round 6
// 257.468 us; speedup vs baseline: 1.4305x; 1.4305x over previous
//
#include <hip/hip_runtime.h>
#include <hip/hip_fp16.h>

// GCNPredictor: 3-layer GCN (sum-aggregation) + sum-pool + MLP head.
// Round 6: R4 gather structure (node-per-lane, col-quarter-per-wave; best
// measured) + fp16 storage for the N x 128 inter-layer features -> halves
// gather/residual/write bytes. All accumulation and GEMMs remain fp32.

constexpr int NUM_GRAPHS = 2048;

// ---------------- h0 = x @ W_emb  ([N,35] @ [35,8]) ----------------
__global__ __launch_bounds__(256) void k_embed(const float* __restrict__ x,
                                               const float* __restrict__ Wemb,
                                               float* __restrict__ h0, int N) {
  __shared__ float sx[32 * 35];
  __shared__ float sw[35 * 8];
  int n0 = blockIdx.x * 32;
  int cnt = min(32, N - n0);
  int nf = cnt * 35;
  for (int i = threadIdx.x; i < nf; i += 256) sx[i] = x[(size_t)n0 * 35 + i];
  for (int i = threadIdx.x; i < 35 * 8; i += 256) sw[i] = Wemb[i];
  __syncthreads();
  int nl = threadIdx.x >> 3;
  int c = threadIdx.x & 7;
  if (nl < cnt) {
    float acc = 0.f;
#pragma unroll
    for (int k = 0; k < 35; ++k) acc = fmaf(sx[nl * 35 + k], sw[k * 8 + c], acc);
    h0[(size_t)(n0 + nl) * 8 + c] = acc;
  }
}

// ---------------- CSR build: counts -> exclusive scan -> fill ----------------
__global__ __launch_bounds__(256) void k_hist(const int* __restrict__ dst,
                                              int* counts, int E) {
  int e = blockIdx.x * 256 + threadIdx.x;
  if (e < E) atomicAdd(&counts[dst[e]], 1);
}

__global__ __launch_bounds__(256) void k_scan1(const int* __restrict__ counts,
                                               int* __restrict__ offs,
                                               int* __restrict__ partials, int N) {
  __shared__ int s[256];
  int i = blockIdx.x * 256 + threadIdx.x;
  int v = (i < N) ? counts[i] : 0;
  s[threadIdx.x] = v;
  __syncthreads();
#pragma unroll
  for (int d = 1; d < 256; d <<= 1) {
    int t = (threadIdx.x >= d) ? s[threadIdx.x - d] : 0;
    __syncthreads();
    s[threadIdx.x] += t;
    __syncthreads();
  }
  if (i < N) offs[i] = s[threadIdx.x] - v;  // exclusive
  if (threadIdx.x == 255) partials[blockIdx.x] = s[255];
}

__global__ __launch_bounds__(512) void k_scan2(int* partials, int nb) {
  __shared__ int s[512];
  int t = threadIdx.x;
  int orig = (t < nb) ? partials[t] : 0;
  s[t] = orig;
  __syncthreads();
#pragma unroll
  for (int d = 1; d < 512; d <<= 1) {
    int v = (t >= d) ? s[t - d] : 0;
    __syncthreads();
    s[t] += v;
    __syncthreads();
  }
  if (t < nb) partials[t] = s[t] - orig;  // exclusive block offsets
}

__global__ __launch_bounds__(256) void k_scan3(int* __restrict__ offs,
                                               const int* __restrict__ partials,
                                               int* __restrict__ cursor, int N) {
  int i = blockIdx.x * 256 + threadIdx.x;
  if (i < N) {
    int v = offs[i] + partials[blockIdx.x];
    offs[i] = v;
    cursor[i] = v;
  }
}

__global__ __launch_bounds__(256) void k_fill(const int* __restrict__ src,
                                              const int* __restrict__ dst,
                                              int* cursor, int* __restrict__ csr,
                                              int E) {
  int e = blockIdx.x * 256 + threadIdx.x;
  if (e < E) {
    int slot = atomicAdd(&cursor[dst[e]], 1);
    csr[slot] = src[e];
  }
}

// -------- layer 0 fused: agg8 = gather(h0); out = relu(agg8 @ W_g0), fp16 out
__global__ __launch_bounds__(256) void k_layer0(const float* __restrict__ h0,
                                                const int* __restrict__ csr,
                                                const int* __restrict__ offs,
                                                const int* __restrict__ cnts,
                                                const float* __restrict__ W,
                                                __half* __restrict__ out, int N) {
  __shared__ float sagg[32 * 9];  // stride 9: conflict-free
  __shared__ float sw[8 * 128];
  for (int i = threadIdx.x; i < 1024; i += 256) sw[i] = W[i];
  int n0 = blockIdx.x * 32;
  {
    int i = threadIdx.x >> 3;
    int c = threadIdx.x & 7;
    int n = n0 + i;
    float acc = 0.f;
    if (n < N) {
      int s = offs[n], cc = cnts[n];
      for (int e = 0; e < cc; ++e) acc += h0[(size_t)csr[s + e] * 8 + c];
    }
    sagg[i * 9 + c] = acc;
  }
  __syncthreads();
  int i2 = threadIdx.x >> 3;
  int j0 = (threadIdx.x & 7) * 16;
  int n2 = n0 + i2;
  if (n2 >= N) return;
  float a[8];
#pragma unroll
  for (int k = 0; k < 8; ++k) a[k] = sagg[i2 * 9 + k];
  float og[16];
#pragma unroll
  for (int j = 0; j < 16; ++j) og[j] = 0.f;
#pragma unroll
  for (int k = 0; k < 8; ++k)
#pragma unroll
    for (int j = 0; j < 16; ++j) og[j] = fmaf(a[k], sw[k * 128 + j0 + j], og[j]);
  size_t base = (size_t)n2 * 128 + j0;
  __half2 o[8];
#pragma unroll
  for (int t4 = 0; t4 < 8; ++t4)
    o[t4] = __floats2half2_rn(fmaxf(og[2 * t4], 0.f), fmaxf(og[2 * t4 + 1], 0.f));
  *reinterpret_cast<float4*>(out + base) = *reinterpret_cast<float4*>(&o[0]);
  *reinterpret_cast<float4*>(out + base + 8) = *reinterpret_cast<float4*>(&o[4]);
}

// accumulate 8 halves (one float4 worth) into two float4 accumulators
__device__ __forceinline__ void acc_half8(float4& a0, float4& a1, float4 v) {
  const __half2* p = reinterpret_cast<const __half2*>(&v);
  float2 f0 = __half22float2(p[0]);
  float2 f1 = __half22float2(p[1]);
  float2 f2 = __half22float2(p[2]);
  float2 f3 = __half22float2(p[3]);
  a0.x += f0.x; a0.y += f0.y; a0.z += f1.x; a0.w += f1.y;
  a1.x += f2.x; a1.y += f2.y; a1.z += f3.x; a1.w += f3.y;
}

// -------- fused GCN layer (d=128, fp16 H): agg = gather(H); v = relu(agg@W)+H
// Gather: wave q (of 4) owns cols [32q,32q+32); lane l owns node n0+l.
// 2 edges per iteration, 8 dwordx4 loads in flight, fp32 accumulation.
// mode 0: out[n] = v (fp16). mode 1: G[gid[n]] += v (pool fused, fp32 G).
__global__ __launch_bounds__(256) void k_gcn_fused(
    const __half* __restrict__ H, const int* __restrict__ csr,
    const int* __restrict__ offs, const int* __restrict__ cnts,
    const float* __restrict__ W, __half* __restrict__ out,
    float* G, const int* __restrict__ gid, int N, int mode) {
  __shared__ float sa[64 * 132];
  int n0 = blockIdx.x * 64;

  // gather phase
  {
    int q = threadIdx.x >> 6;  // column quarter
    int l = threadIdx.x & 63;  // node lane
    int n = n0 + l;
    float4 acc[8];
#pragma unroll
    for (int i = 0; i < 8; ++i) acc[i] = make_float4(0.f, 0.f, 0.f, 0.f);
    int cnt = (n < N) ? cnts[n] : 0;
    int s = (n < N) ? offs[n] : 0;
    const __half* Hq = H + q * 32;
    int e = 0;
    for (; e + 2 <= cnt; e += 2) {
      int s0 = csr[s + e], s1 = csr[s + e + 1];
      const float4* r0 = reinterpret_cast<const float4*>(Hq + (size_t)s0 * 128);
      const float4* r1 = reinterpret_cast<const float4*>(Hq + (size_t)s1 * 128);
      float4 a0 = r0[0], a1 = r0[1], a2 = r0[2], a3 = r0[3];
      float4 b0 = r1[0], b1 = r1[1], b2 = r1[2], b3 = r1[3];
      acc_half8(acc[0], acc[1], a0);
      acc_half8(acc[2], acc[3], a1);
      acc_half8(acc[4], acc[5], a2);
      acc_half8(acc[6], acc[7], a3);
      acc_half8(acc[0], acc[1], b0);
      acc_half8(acc[2], acc[3], b1);
      acc_half8(acc[4], acc[5], b2);
      acc_half8(acc[6], acc[7], b3);
    }
    if (e < cnt) {
      int s0 = csr[s + e];
      const float4* r0 = reinterpret_cast<const float4*>(Hq + (size_t)s0 * 128);
      float4 a0 = r0[0], a1 = r0[1], a2 = r0[2], a3 = r0[3];
      acc_half8(acc[0], acc[1], a0);
      acc_half8(acc[2], acc[3], a1);
      acc_half8(acc[4], acc[5], a2);
      acc_half8(acc[6], acc[7], a3);
    }
    float* srow = &sa[l * 132 + q * 32];
#pragma unroll
    for (int i = 0; i < 8; ++i)
      *reinterpret_cast<float4*>(srow + 4 * i) = acc[i];
  }
  __syncthreads();

  // GEMM 64x128 @ 128x128 (fp32)
  int nl = threadIdx.x >> 4;
  int j0 = (threadIdx.x & 15) * 8;
  float acc[4][8];
#pragma unroll
  for (int r = 0; r < 4; ++r)
#pragma unroll
    for (int j = 0; j < 8; ++j) acc[r][j] = 0.f;
  const float* Wj = W + j0;
#pragma unroll 2
  for (int k = 0; k < 128; ++k) {
    float4 w0 = *reinterpret_cast<const float4*>(Wj + (size_t)k * 128);
    float4 w1 = *reinterpret_cast<const float4*>(Wj + (size_t)k * 128 + 4);
    float wv[8] = {w0.x, w0.y, w0.z, w0.w, w1.x, w1.y, w1.z, w1.w};
#pragma unroll
    for (int r = 0; r < 4; ++r) {
      float a = sa[(nl + 16 * r) * 132 + k];
#pragma unroll
      for (int j = 0; j < 8; ++j) acc[r][j] = fmaf(a, wv[j], acc[r][j]);
    }
  }

  if (mode == 0) {
#pragma unroll
    for (int r = 0; r < 4; ++r) {
      int row = nl + 16 * r;
      int n = n0 + row;
      if (n < N) {
        size_t base = (size_t)n * 128 + j0;
        float4 hv = *reinterpret_cast<const float4*>(H + base);
        const __half2* hp = reinterpret_cast<const __half2*>(&hv);
        float2 f0 = __half22float2(hp[0]);
        float2 f1 = __half22float2(hp[1]);
        float2 f2 = __half22float2(hp[2]);
        float2 f3 = __half22float2(hp[3]);
        __half2 ov[4];
        ov[0] = __floats2half2_rn(fmaxf(acc[r][0], 0.f) + f0.x,
                                  fmaxf(acc[r][1], 0.f) + f0.y);
        ov[1] = __floats2half2_rn(fmaxf(acc[r][2], 0.f) + f1.x,
                                  fmaxf(acc[r][3], 0.f) + f1.y);
        ov[2] = __floats2half2_rn(fmaxf(acc[r][4], 0.f) + f2.x,
                                  fmaxf(acc[r][5], 0.f) + f2.y);
        ov[3] = __floats2half2_rn(fmaxf(acc[r][6], 0.f) + f3.x,
                                  fmaxf(acc[r][7], 0.f) + f3.y);
        *reinterpret_cast<float4*>(out + base) = *reinterpret_cast<float4*>(ov);
      }
    }
  } else {
    __syncthreads();  // all GEMM reads of sa done
#pragma unroll
    for (int r = 0; r < 4; ++r) {
      int row = nl + 16 * r;
      int n = n0 + row;
      if (n < N) {
        size_t base = (size_t)n * 128 + j0;
        float4 hv = *reinterpret_cast<const float4*>(H + base);
        const __half2* hp = reinterpret_cast<const __half2*>(&hv);
        float2 f0 = __half22float2(hp[0]);
        float2 f1 = __half22float2(hp[1]);
        float2 f2 = __half22float2(hp[2]);
        float2 f3 = __half22float2(hp[3]);
        float* srow = &sa[row * 132 + j0];
        srow[0] = fmaxf(acc[r][0], 0.f) + f0.x;
        srow[1] = fmaxf(acc[r][1], 0.f) + f0.y;
        srow[2] = fmaxf(acc[r][2], 0.f) + f1.x;
        srow[3] = fmaxf(acc[r][3], 0.f) + f1.y;
        srow[4] = fmaxf(acc[r][4], 0.f) + f2.x;
        srow[5] = fmaxf(acc[r][5], 0.f) + f2.y;
        srow[6] = fmaxf(acc[r][6], 0.f) + f3.x;
        srow[7] = fmaxf(acc[r][7], 0.f) + f3.y;
      }
    }
    __syncthreads();
    int grp = threadIdx.x >> 7;  // 0..1 -> rows [0,32) / [32,64)
    int j = threadIdx.x & 127;
    int r0 = grp * 32;
    int nfirst = n0 + r0;
    if (nfirst < N) {
      float pacc = 0.f;
      int cur = gid[nfirst];
      for (int r = r0; r < r0 + 32; ++r) {
        int n = n0 + r;
        if (n >= N) break;
        int g2 = gid[n];
        if (g2 != cur) {
          atomicAdd(&G[(size_t)cur * 128 + j], pacc);
          pacc = 0.f;
          cur = g2;
        }
        pacc += sa[r * 132 + j];
      }
      atomicAdd(&G[(size_t)cur * 128 + j], pacc);
    }
  }
}

// ---------------- pred = relu(g @ W_p1) @ W_p2 + b ----------------
__global__ __launch_bounds__(64) void k_head(const float* __restrict__ g,
                                             const float* __restrict__ W1,
                                             const float* __restrict__ W2,
                                             const float* __restrict__ b,
                                             float* __restrict__ out) {
  int gi = blockIdx.x;
  int j = threadIdx.x;
  __shared__ float sg[128];
  sg[j] = g[(size_t)gi * 128 + j];
  sg[j + 64] = g[(size_t)gi * 128 + 64 + j];
  __syncthreads();
  float acc = 0.f;
#pragma unroll
  for (int k = 0; k < 128; ++k) acc = fmaf(sg[k], W1[k * 64 + j], acc);
  acc = fmaxf(acc, 0.f) * W2[j];
#pragma unroll
  for (int off = 32; off > 0; off >>= 1) acc += __shfl_down(acc, off);
  if (j == 0) out[gi] = acc + b[0];
}

extern "C" void kernel_launch(void* const* d_in, const int* in_sizes, int n_in,
                              void* d_out, int out_size, void* d_ws, size_t ws_size,
                              hipStream_t stream) {
  const float* x    = (const float*)d_in[0];
  const float* Wemb = (const float*)d_in[1];
  const float* Wg0  = (const float*)d_in[2];
  const float* Wg1  = (const float*)d_in[3];
  const float* Wg2  = (const float*)d_in[4];
  const float* Wp1  = (const float*)d_in[5];
  const float* Wp2  = (const float*)d_in[6];
  const float* bp2  = (const float*)d_in[7];
  const int* esrc   = (const int*)d_in[8];
  const int* edst   = (const int*)d_in[9];
  const int* gids   = (const int*)d_in[10];
  int N = in_sizes[0] / 35;
  int E = in_sizes[8];
  float* out = (float*)d_out;

  // workspace layout (bytes)
  char* wp = (char*)d_ws;
  float* h0 = (float*)wp;            wp += (size_t)N * 8 * sizeof(float);
  __half* P = (__half*)wp;           wp += (size_t)N * 128 * sizeof(__half);
  __half* Q = (__half*)wp;           wp += (size_t)N * 128 * sizeof(__half);
  float* G  = (float*)wp;            wp += (size_t)NUM_GRAPHS * 128 * sizeof(float);
  int* counts   = (int*)wp;          wp += (size_t)N * sizeof(int);
  int* offs     = (int*)wp;          wp += (size_t)N * sizeof(int);
  int* cursor   = (int*)wp;          wp += (size_t)N * sizeof(int);
  int* partials = (int*)wp;          wp += 512 * sizeof(int);
  int* csr      = (int*)wp;

  int nbE = (E + 255) / 256;
  int nbN = (N + 255) / 256;

  // embed (independent)
  k_embed<<<(N + 31) / 32, 256, 0, stream>>>(x, Wemb, h0, N);

  // CSR build
  hipMemsetAsync(counts, 0, (size_t)N * sizeof(int), stream);
  k_hist<<<nbE, 256, 0, stream>>>(edst, counts, E);
  k_scan1<<<nbN, 256, 0, stream>>>(counts, offs, partials, N);
  k_scan2<<<1, 512, 0, stream>>>(partials, nbN);
  k_scan3<<<nbN, 256, 0, stream>>>(offs, partials, cursor, N);
  k_fill<<<nbE, 256, 0, stream>>>(esrc, edst, cursor, csr, E);

  // zero pooled output (layer-2 epilogue atomics accumulate into it)
  hipMemsetAsync(G, 0, (size_t)NUM_GRAPHS * 128 * sizeof(float), stream);

  // layer 0: P = relu(gather(h0) @ W_g0)   (fp16 out)
  k_layer0<<<(N + 31) / 32, 256, 0, stream>>>(h0, csr, offs, counts, Wg0, P, N);

  // layer 1: Q = relu(gather(P) @ W_g1) + P
  k_gcn_fused<<<(N + 63) / 64, 256, 0, stream>>>(P, csr, offs, counts, Wg1, Q,
                                                 nullptr, nullptr, N, 0);

  // layer 2 + pool: G[gid] += relu(gather(Q) @ W_g2) + Q
  k_gcn_fused<<<(N + 63) / 64, 256, 0, stream>>>(Q, csr, offs, counts, Wg2, nullptr,
                                                 G, gids, N, 1);

  // head
  k_head<<<NUM_GRAPHS, 64, 0, stream>>>(G, Wp1, Wp2, bp2, out);
}